// Round 1
// baseline (8556.437 us; speedup 1.0000x reference)
//
#include <hip/hip_runtime.h>
#include <hip/hip_bf16.h>

// Problem constants
#define BB   64      // batch
#define NCC  512     // cells
#define TT   1024    // time steps (32x32 raster)
#define KPAD 1088    // 64 (x padded from 48) + 512 (prev2) + 512 (h)
#define RING_SLOTS 64
#define GWG  128     // step-kernel workgroups; each owns 4 cells (16 gate rows)
#define WSTRIDE 1096 // KPAD + 8 bf16 pad to break LDS bank alignment

typedef __attribute__((ext_vector_type(8))) short short8;
typedef __attribute__((ext_vector_type(4))) float floatx4;
using bf16 = __hip_bfloat16;

__device__ __forceinline__ float fast_sigmoid(float x) {
    return 1.f / (1.f + __expf(-x));
}
__device__ __forceinline__ float fast_tanh(float x) {
    float e = __expf(2.f * fminf(fmaxf(x, -15.f), 15.f));
    return (e - 1.f) / (e + 1.f);
}

// Build combined bf16 weight matrix Wc[row][k], k: [0,48)=W_ih x-part, [48,64)=0,
// [64,576)=W_ih prev2-part, [576,1088)=W_hh. Also bias = b_ih + b_hh (fp32).
__global__ void prep_wb(const float* __restrict__ Wih, const float* __restrict__ Whh,
                        const float* __restrict__ bih, const float* __restrict__ bhh,
                        bf16* __restrict__ Wc, float* __restrict__ bias) {
    int idx = blockIdx.x * 256 + threadIdx.x;
    int total = 2048 * KPAD;
    if (idx < total) {
        int row = idx / KPAD;
        int k = idx - row * KPAD;
        float v = 0.f;
        if (k < 48)       v = Wih[row * 560 + k];
        else if (k < 64)  v = 0.f;
        else if (k < 576) v = Wih[row * 560 + 48 + (k - 64)];
        else              v = Whh[row * 512 + (k - 576)];
        Wc[idx] = __float2bfloat16(v);
    }
    if (idx < 2048) bias[idx] = bih[idx] + bhh[idx];
}

// Extract patches: xs[t][b][kk] (kk = c*16 + py*4 + px, padded 48->64 with zeros), bf16.
__global__ void prep_x(const float* __restrict__ batch, bf16* __restrict__ xs) {
    int idx = blockIdx.x * 256 + threadIdx.x;   // exactly 1024*64*64 threads
    int kk = idx & 63;
    int b  = (idx >> 6) & 63;
    int t  = idx >> 12;
    float v = 0.f;
    if (kk < 48) {
        int c = kk >> 4, py = (kk >> 2) & 3, px = kk & 3;
        int i = t >> 5, j = t & 31;
        v = batch[((b * 3 + c) * 128 + (i * 4 + py)) * 128 + (j * 4 + px)];
    }
    xs[idx] = __float2bfloat16(v);
}

// One LSTM step. WG wg owns cells n = wg*4 .. wg*4+3 -> 16 gate rows
// (row n16: gate=n16>>2, cell=n16&3; global row = gate*512 + wg*4 + cell).
// 4 waves: wave w computes batches w*16..w*16+15 for all 16 rows via
// mfma_f32_16x16x32_bf16, K=1088 = 34 iters.
__launch_bounds__(256, 1)
__global__ void step_kernel(const bf16* __restrict__ Wc, const float* __restrict__ bias,
                            const bf16* __restrict__ xs, bf16* __restrict__ ring,
                            float* __restrict__ cst, float* __restrict__ out, int t)
{
    __shared__ short lw[16 * WSTRIDE];
    __shared__ float gsm[64 * 16];

    const int wg  = blockIdx.x;
    const int tid = threadIdx.x;

    // ---- stage 16 weight rows into LDS (coalesced 16B chunks) ----
    {
        int n16  = tid >> 4;        // 0..15 row
        int tcol = tid & 15;        // 16 threads per row
        int grow = ((n16 >> 2) * 512) + wg * 4 + (n16 & 3);
        const short* src = (const short*)(Wc + grow * KPAD);
        short* dst = &lw[n16 * WSTRIDE];
        #pragma unroll
        for (int ck = tcol; ck < KPAD / 8; ck += 16) {
            *(short8*)(dst + ck * 8) = *(const short8*)(src + ck * 8);
        }
    }
    __syncthreads();

    const int lane = tid & 63;
    const int w    = tid >> 6;       // wave id 0..3 (M tile)
    const int mrow = lane & 15;      // A: batch-in-tile; B/D: gate row n16
    const int quad = lane >> 4;
    const int b    = w * 16 + mrow;  // batch for A fragment

    const int slot_p2 = t & 63;         // h from t-32 (zeros for t<32)
    const int slot_p1 = (t + 31) & 63;  // h from t-1  (zeros for t=0)
    const int wslot   = (t + 32) & 63;  // this step's h slot

    const short* wl    = &lw[mrow * WSTRIDE + quad * 8];
    const short* xrow  = (const short*)(xs   + (t * 64 + b) * 64) + quad * 8;
    const short* p2row = (const short*)(ring + (slot_p2 * 64 + b) * 512) + quad * 8;
    const short* p1row = (const short*)(ring + (slot_p1 * 64 + b) * 512) + quad * 8;

    floatx4 acc = {0.f, 0.f, 0.f, 0.f};
    #pragma unroll
    for (int it = 0; it < 2; ++it) {   // x region, k0 in [0,64)
        short8 a  = *(const short8*)(xrow + it * 32);
        short8 bf = *(const short8*)(wl + it * 32);
        acc = __builtin_amdgcn_mfma_f32_16x16x32_bf16(a, bf, acc, 0, 0, 0);
    }
    #pragma unroll
    for (int it = 2; it < 18; ++it) {  // prev2 region, k0 in [64,576)
        short8 a  = *(const short8*)(p2row + (it * 32 - 64));
        short8 bf = *(const short8*)(wl + it * 32);
        acc = __builtin_amdgcn_mfma_f32_16x16x32_bf16(a, bf, acc, 0, 0, 0);
    }
    #pragma unroll
    for (int it = 18; it < 34; ++it) { // h region, k0 in [576,1088)
        short8 a  = *(const short8*)(p1row + (it * 32 - 576));
        short8 bf = *(const short8*)(wl + it * 32);
        acc = __builtin_amdgcn_mfma_f32_16x16x32_bf16(a, bf, acc, 0, 0, 0);
    }

    // D layout: lane holds D[m = quad*4 + r][n = mrow]; m = batch-in-tile.
    float bsr = bias[((mrow >> 2) * 512) + wg * 4 + (mrow & 3)];
    #pragma unroll
    for (int r = 0; r < 4; ++r) {
        int bm = w * 16 + quad * 4 + r;
        gsm[bm * 16 + mrow] = acc[r] + bsr;
    }
    __syncthreads();

    // ---- LSTM cell: thread -> (batch b2, cell) ----
    const int cell = tid & 3;
    const int b2   = tid >> 2;
    const int n    = wg * 4 + cell;
    float gi = gsm[b2 * 16 + 0  + cell];
    float gf = gsm[b2 * 16 + 4  + cell];
    float gg = gsm[b2 * 16 + 8  + cell];
    float go = gsm[b2 * 16 + 12 + cell];
    float c_old = cst[b2 * 512 + n];
    float cn = fast_sigmoid(gf) * c_old + fast_sigmoid(gi) * fast_tanh(gg);
    float h  = fast_sigmoid(go) * fast_tanh(cn);
    cst[b2 * 512 + n] = cn;
    ring[(wslot * 64 + b2) * 512 + n] = __float2bfloat16(h);
    // out is (B, T, NC) flat (the reference reshape is a flat reinterpretation)
    out[(b2 * 1024 + t) * 512 + n] = h;
}

extern "C" void kernel_launch(void* const* d_in, const int* in_sizes, int n_in,
                              void* d_out, int out_size, void* d_ws, size_t ws_size,
                              hipStream_t stream) {
    const float* batch = (const float*)d_in[0];
    const float* Wih   = (const float*)d_in[1];
    const float* Whh   = (const float*)d_in[2];
    const float* bih   = (const float*)d_in[3];
    const float* bhh   = (const float*)d_in[4];
    float* out = (float*)d_out;

    char* p = (char*)d_ws;
    bf16*  Wc   = (bf16*)p;  p += (size_t)2048 * KPAD * 2;          // 4,456,448
    float* bias = (float*)p; p += (size_t)2048 * 4;                 // 8,192
    bf16*  xs   = (bf16*)p;  p += (size_t)TT * 64 * 64 * 2;         // 8,388,608
    bf16*  ring = (bf16*)p;  p += (size_t)RING_SLOTS * 64 * 512 * 2;// 4,194,304
    float* cst  = (float*)p; p += (size_t)64 * 512 * 4;             // 131,072
    // total ~17.2 MB of ws

    // zero the first 32 ring slots (prev2 for t<32 and h(-1)) and c-state
    hipMemsetAsync(ring, 0, (size_t)32 * 64 * 512 * 2, stream);
    hipMemsetAsync(cst,  0, (size_t)64 * 512 * 4, stream);

    prep_wb<<<(2048 * KPAD + 255) / 256, 256, 0, stream>>>(Wih, Whh, bih, bhh, Wc, bias);
    prep_x<<<(TT * 64 * 64) / 256, 256, 0, stream>>>(batch, xs);

    for (int t = 0; t < TT; ++t) {
        step_kernel<<<GWG, 256, 0, stream>>>(Wc, bias, xs, ring, cst, out, t);
    }
}